// Round 5
// baseline (531.675 us; speedup 1.0000x reference)
//
#include <hip/hip_runtime.h>
#include <hip/hip_bf16.h>
#include <cstdint>
#include <cstddef>

#define FIN 500
#define FH  128
#define FOUT 40

typedef __attribute__((ext_vector_type(8))) short short8;
typedef __attribute__((ext_vector_type(4))) float f32x4;

__device__ inline float bf_lo(unsigned v) { unsigned t = v << 16; return __builtin_bit_cast(float, t); }
__device__ inline float bf_hi(unsigned v) { unsigned t = v & 0xffff0000u; return __builtin_bit_cast(float, t); }
__device__ inline unsigned short f2bf_bits(float f) {
  __hip_bfloat16 b = __float2bfloat16(f);
  return __builtin_bit_cast(unsigned short, b);
}

// ---------------- CSR build ----------------

__global__ void k_hist(const int* __restrict__ dst, int* __restrict__ cnt, int E) {
  int e = blockIdx.x * 256 + threadIdx.x;
  if (e < E) atomicAdd(&cnt[dst[e]], 1);
}

__global__ void k_dis(const int* __restrict__ cnt, float* __restrict__ dis, int n) {
  int i = blockIdx.x * 256 + threadIdx.x;
  if (i < n) dis[i] = rsqrtf((float)cnt[i] + 1.0f);  // deg includes self-loop
}

__global__ void k_scan1(const int* __restrict__ cnt, int* __restrict__ rp,
                        int* __restrict__ bsums, int n) {
  __shared__ int sums[256];
  int t = threadIdx.x;
  int base = blockIdx.x * 1024;
  int c[4]; int tot = 0;
#pragma unroll
  for (int j = 0; j < 4; ++j) {
    int idx = base + t * 4 + j;
    c[j] = (idx < n) ? cnt[idx] : 0;
    tot += c[j];
  }
  sums[t] = tot;
  __syncthreads();
  for (int off = 1; off < 256; off <<= 1) {
    int v = 0;
    if (t >= off) v = sums[t - off];
    __syncthreads();
    if (t >= off) sums[t] += v;
    __syncthreads();
  }
  int run = sums[t] - tot;
#pragma unroll
  for (int j = 0; j < 4; ++j) {
    int idx = base + t * 4 + j;
    if (idx < n) rp[idx] = run;
    run += c[j];
  }
  if (t == 255) bsums[blockIdx.x] = sums[255];
}

__global__ void k_scan2(int* __restrict__ bsums, int nb) {
  __shared__ int s[256];
  int t = threadIdx.x;
  int v = (t < nb) ? bsums[t] : 0;
  s[t] = v;
  __syncthreads();
  for (int off = 1; off < 256; off <<= 1) {
    int u = 0;
    if (t >= off) u = s[t - off];
    __syncthreads();
    if (t >= off) s[t] += u;
    __syncthreads();
  }
  if (t < nb) bsums[t] = s[t] - v;  // exclusive
}

__global__ void k_scan3(int* __restrict__ rp, const int* __restrict__ bsums, int n, int E) {
  int idx = blockIdx.x * 256 + threadIdx.x;
  if (idx < n) rp[idx] += bsums[idx >> 10];
  if (idx == n) rp[n] = E;
}

// scatter edges to CSR order; esrc = byte offset into hQ (128B rows), enorm = dis[s]*dis[d]
__global__ void k_scatter(const int* __restrict__ src, const int* __restrict__ dst,
                          const float* __restrict__ dis,
                          const int* __restrict__ rp, int* __restrict__ fill,
                          int* __restrict__ esrc, float* __restrict__ enorm, int E) {
  int e = blockIdx.x * 256 + threadIdx.x;
  if (e >= E) return;
  int d = dst[e], s = src[e];
  int pos = rp[d] + atomicAdd(&fill[d], 1);
  esrc[pos] = s << 7;                 // s * 128
  enorm[pos] = dis[s] * dis[d];
}

// per-layer: fold row scale into edge weight -> epackL = (byte_off, norm*scale[src])
__global__ void k_rescale(const int* __restrict__ esrc, const float* __restrict__ enorm,
                          const float* __restrict__ scale, int2* __restrict__ epackL, int E) {
  int e = blockIdx.x * 256 + threadIdx.x;
  if (e >= E) return;
  int off = esrc[e];
  float n = enorm[e] * scale[off >> 7];
  epackL[e] = make_int2(off, __builtin_bit_cast(int, n));
}

// ---------------- weight prep ----------------

__global__ void k_prep_w(const float* __restrict__ W, short* __restrict__ WT, int K, int KPAD) {
  int idx = blockIdx.x * 256 + threadIdx.x;
  if (idx >= 128 * KPAD) return;
  int c = idx / KPAD, k = idx - c * KPAD;
  WT[idx] = (k < K) ? (short)f2bf_bits(W[(size_t)k * FH + c]) : (short)0;
}

// WfcT[48][128] bf16 from Wfc[128][40] f32, zero-padded cols 40..47
__global__ void k_prep_wfc(const float* __restrict__ Wfc, short* __restrict__ WfcT) {
  int idx = blockIdx.x * 256 + threadIdx.x;
  if (idx >= 48 * 128) return;
  int c = idx >> 7, k = idx & 127;
  WfcT[idx] = (c < FOUT) ? (short)f2bf_bits(Wfc[(size_t)k * FOUT + c]) : (short)0;
}

// ---------------- per-row int8 quantize: hA(bf16) -> hQ(int8) + scale ----------------
// one wave per node; lane covers features 2*lane, 2*lane+1.

__global__ void __launch_bounds__(256) k_quant(const unsigned* __restrict__ hA,
                                               unsigned short* __restrict__ hQ,
                                               float* __restrict__ scale, int N) {
  int node = blockIdx.x * 4 + (threadIdx.x >> 6);
  int lane = threadIdx.x & 63;
  if (node >= N) return;
  unsigned v = hA[(size_t)node * 64 + lane];
  float lo = bf_lo(v), hi = bf_hi(v);
  float m = fmaxf(fabsf(lo), fabsf(hi));
#pragma unroll
  for (int s = 1; s < 64; s <<= 1) m = fmaxf(m, __shfl_xor(m, s));
  float rs = (m > 0.f) ? 127.f / m : 0.f;
  int q0 = (int)rintf(lo * rs), q1 = (int)rintf(hi * rs);
  hQ[(size_t)node * 64 + lane] = (unsigned short)((q0 & 0xff) | ((q1 & 0xff) << 8));
  if (lane == 0) scale[node] = m * (1.f / 127.f);
}

// ---------------- MFMA GEMM: C[M][128](bf16) = A[M][K] @ WT^T ----------------
// BM=64, BN=128, BK=32, 256 threads (4 waves 2x2). Double-buffered LDS:
// one barrier per K-step; tile t+1 global loads issued before tile t's MFMA.

template<bool AF32>
__global__ void __launch_bounds__(256) k_gemm_mfma(const void* __restrict__ Aptr,
                                                   const short* __restrict__ WT,
                                                   short* __restrict__ C,
                                                   int M, int K, int KPAD) {
  __shared__ char sA[2][64 * 80];
  __shared__ char sB[2][128 * 80];
  const int tid = threadIdx.x;
  const int r0 = blockIdx.x * 64;
  const int wave = tid >> 6, lane = tid & 63;
  const int wm = wave >> 1, wn = wave & 1;
  const int lr = lane & 15, g = lane >> 4;
  const int arow = tid >> 2, aq = tid & 3;   // A staging: row 0..63, 8 k-elems each
  const int bcol = tid >> 1, bh = tid & 1;   // B staging: col 0..127, 16 k-elems each

  f32x4 acc[2][4];
#pragma unroll
  for (int i = 0; i < 2; ++i)
#pragma unroll
    for (int j = 0; j < 4; ++j) acc[i][j] = (f32x4){0.f, 0.f, 0.f, 0.f};

  const int nkt = (K + 31) / 32;
  const int agr = (r0 + arow < M) ? (r0 + arow) : (M - 1);  // clamp; stores guarded

  float4 fa0, fa1;   // AF32 prefetch regs
  short8 abf;        // bf16 prefetch
  short8 b0, b1;

  auto loadA = [&](int kt) {
    const int k0 = kt * 32 + aq * 8;
    if (AF32) {
      const float* A = (const float*)Aptr;
      if (k0 + 8 <= K) {
        const float4* ap = (const float4*)(A + (size_t)agr * K + k0);
        fa0 = ap[0]; fa1 = ap[1];
      } else {
        const float* ap = A + (size_t)agr * K;
        float t[8];
#pragma unroll
        for (int j = 0; j < 8; ++j) t[j] = (k0 + j < K) ? ap[k0 + j] : 0.f;
        fa0 = make_float4(t[0], t[1], t[2], t[3]);
        fa1 = make_float4(t[4], t[5], t[6], t[7]);
      }
    } else {
      const short* A = (const short*)Aptr;   // K multiple of 32
      abf = *(const short8*)(A + (size_t)agr * K + k0);
    }
  };
  auto loadB = [&](int kt) {
    const int k0 = kt * 32 + bh * 16;
    const short8* wp = (const short8*)(WT + (size_t)bcol * KPAD + k0);
    b0 = wp[0]; b1 = wp[1];
  };
  auto stageLDS = [&](int buf) {
    short8 av;
    if (AF32) {
      float f[8] = {fa0.x, fa0.y, fa0.z, fa0.w, fa1.x, fa1.y, fa1.z, fa1.w};
#pragma unroll
      for (int j = 0; j < 8; ++j) av[j] = (short)f2bf_bits(f[j]);
    } else {
      av = abf;
    }
    *(short8*)(sA[buf] + arow * 80 + aq * 16) = av;
    *(short8*)(sB[buf] + bcol * 80 + bh * 32) = b0;
    *(short8*)(sB[buf] + bcol * 80 + bh * 32 + 16) = b1;
  };

  loadA(0); loadB(0);
  stageLDS(0);
  __syncthreads();
  for (int kt = 0; kt < nkt; ++kt) {
    const int cur = kt & 1;
    if (kt + 1 < nkt) { loadA(kt + 1); loadB(kt + 1); }
    short8 af[2], bfr[4];
#pragma unroll
    for (int i = 0; i < 2; ++i)
      af[i] = *(const short8*)(sA[cur] + (wm * 32 + i * 16 + lr) * 80 + g * 16);
#pragma unroll
    for (int j = 0; j < 4; ++j)
      bfr[j] = *(const short8*)(sB[cur] + (wn * 64 + j * 16 + lr) * 80 + g * 16);
#pragma unroll
    for (int i = 0; i < 2; ++i)
#pragma unroll
      for (int j = 0; j < 4; ++j)
        acc[i][j] = __builtin_amdgcn_mfma_f32_16x16x32_bf16(af[i], bfr[j], acc[i][j], 0, 0, 0);
    if (kt + 1 < nkt) stageLDS(cur ^ 1);
    __syncthreads();
  }
  // epilogue: C/D layout col=lane&15, row=(lane>>4)*4+reg
#pragma unroll
  for (int i = 0; i < 2; ++i) {
#pragma unroll
    for (int reg = 0; reg < 4; ++reg) {
      int gr = r0 + wm * 32 + i * 16 + g * 4 + reg;
      if (gr < M) {
#pragma unroll
        for (int j = 0; j < 4; ++j) {
          int gc = wn * 64 + j * 16 + lr;
          C[(size_t)gr * FH + gc] = (short)f2bf_bits(acc[i][j][reg]);
        }
      }
    }
  }
}

// ---------------- aggregation v4: int8 gather (128B/edge), fp32 accum ----------------
// One wave per node. Lanes 0-31 take even edges, 32-63 odd edges; each lane
// loads one dword = 4 int8 features. Edge packs (byte_off, norm*scale) loaded
// by lanes 0-15, distributed via ds_bpermute. Self term from bf16 hA.
// Final shfl_xor(32) combines edge-parity halves.

__global__ void __launch_bounds__(256) k_agg(const char* __restrict__ hQbytes,
                                             const char* __restrict__ hAbytes,
                                             char* __restrict__ outbytes,
                                             const float* __restrict__ dis,
                                             const int* __restrict__ rp,
                                             const int2* __restrict__ epackL,
                                             const float* __restrict__ bias,
                                             int N) {
  int node = blockIdx.x * 4 + (threadIdx.x >> 6);
  int lane = threadIdx.x & 63;
  if (node >= N) return;
  const int q = lane & 31;       // dword index within the 128B int8 row
  const int hi = lane >> 5;      // 0: even edges, 1: odd edges
  float a0 = 0.f, a1 = 0.f, a2 = 0.f, a3 = 0.f;
  if (hi == 0) {                 // self term once (halves are summed later)
    float w = dis[node]; w = w * w;
    uint2 sv = *(const uint2*)(hAbytes + (size_t)node * 256 + q * 8);
    a0 = w * bf_lo(sv.x); a1 = w * bf_hi(sv.x);
    a2 = w * bf_lo(sv.y); a3 = w * bf_hi(sv.y);
  }
  const int vbp = hi * 4;        // ds_bpermute byte addr base: lane 2j+hi
  const int end = rp[node + 1];
  for (int e = rp[node]; e < end; e += 16) {
    int rem = end - e;
    int2 p = make_int2(0, 0);
    if (lane < 16 && lane < rem) p = epackL[e + lane];
    int vv[8]; float nn[8];
#pragma unroll
    for (int j = 0; j < 8; ++j) {
      int idx4 = vbp + 8 * j;
      int off = __builtin_amdgcn_ds_bpermute(idx4, p.x);
      int nb  = __builtin_amdgcn_ds_bpermute(idx4, p.y);
      nn[j] = __builtin_bit_cast(float, nb);
      vv[j] = *(const int*)(hQbytes + (size_t)(unsigned)(off + q * 4));
    }
#pragma unroll
    for (int j = 0; j < 8; ++j) {
      int d = vv[j];
      float n = nn[j];
      a0 += n * (float)((d << 24) >> 24);
      a1 += n * (float)((d << 16) >> 24);
      a2 += n * (float)((d << 8) >> 24);
      a3 += n * (float)(d >> 24);
    }
  }
  a0 += __shfl_xor(a0, 32); a1 += __shfl_xor(a1, 32);
  a2 += __shfl_xor(a2, 32); a3 += __shfl_xor(a3, 32);
  if (hi == 0) {
    float4 bv = *(const float4*)(bias + 4 * q);
    a0 = fmaxf(a0 + bv.x, 0.f); a1 = fmaxf(a1 + bv.y, 0.f);
    a2 = fmaxf(a2 + bv.z, 0.f); a3 = fmaxf(a3 + bv.w, 0.f);
    uint2 r;
    r.x = ((unsigned)f2bf_bits(a1) << 16) | (unsigned)f2bf_bits(a0);
    r.y = ((unsigned)f2bf_bits(a3) << 16) | (unsigned)f2bf_bits(a2);
    *(uint2*)(outbytes + (size_t)node * 256 + q * 8) = r;
  }
}

// ---------------- fused logits + log_softmax via MFMA ----------------

__global__ void __launch_bounds__(256) k_logits(const short* __restrict__ h,     // bf16 [N][128]
                                                const short* __restrict__ WfcT,  // bf16 [48][128]
                                                const float* __restrict__ bfc,
                                                float* __restrict__ out, int N) {
  const int wave = threadIdx.x >> 6, lane = threadIdx.x & 63;
  const int lr = lane & 15, g = lane >> 4;
  const int nbase = blockIdx.x * 64 + wave * 16;
  int arow = nbase + lr; if (arow >= N) arow = N - 1;
  const short* ap = h + (size_t)arow * FH;
  short8 af[4];
#pragma unroll
  for (int ks = 0; ks < 4; ++ks)
    af[ks] = *(const short8*)(ap + ks * 32 + g * 8);
  f32x4 acc[3];
#pragma unroll
  for (int t = 0; t < 3; ++t) {
    acc[t] = (f32x4){0.f, 0.f, 0.f, 0.f};
    const short* bp = WfcT + (size_t)(t * 16 + lr) * FH;
#pragma unroll
    for (int ks = 0; ks < 4; ++ks) {
      short8 bf = *(const short8*)(bp + ks * 32 + g * 8);
      acc[t] = __builtin_amdgcn_mfma_f32_16x16x32_bf16(af[ks], bf, acc[t], 0, 0, 0);
    }
  }
  float bb[3];
#pragma unroll
  for (int t = 0; t < 3; ++t) { int c = t * 16 + lr; bb[t] = (c < FOUT) ? bfc[c] : 0.f; }
  const bool v2 = (lr < 8);  // tile 2 valid classes: 32..39
  float res[3][4];
#pragma unroll
  for (int r = 0; r < 4; ++r) {
    float l0 = acc[0][r] + bb[0];
    float l1 = acc[1][r] + bb[1];
    float l2 = v2 ? (acc[2][r] + bb[2]) : -INFINITY;
    float mm = fmaxf(fmaxf(l0, l1), l2);
#pragma unroll
    for (int s = 1; s < 16; s <<= 1) mm = fmaxf(mm, __shfl_xor(mm, s));
    float e0 = expf(l0 - mm), e1 = expf(l1 - mm), e2 = v2 ? expf(l2 - mm) : 0.f;
    float ss = e0 + e1 + e2;
#pragma unroll
    for (int s = 1; s < 16; s <<= 1) ss += __shfl_xor(ss, s);
    float lse = mm + logf(ss);
    res[0][r] = l0 - lse; res[1][r] = l1 - lse; res[2][r] = l2 - lse;
  }
#pragma unroll
  for (int t = 0; t < 3; ++t) {
    int c = t * 16 + lr;
    if (c < FOUT) {
#pragma unroll
      for (int r = 0; r < 4; ++r) {
        int node = nbase + g * 4 + r;
        if (node < N) out[(size_t)node * FOUT + c] = res[t][r];
      }
    }
  }
}

// ---------------- host ----------------

static inline size_t align_up(size_t x, size_t a) { return (x + a - 1) & ~(a - 1); }

extern "C" void kernel_launch(void* const* d_in, const int* in_sizes, int n_in,
                              void* d_out, int out_size, void* d_ws, size_t ws_size,
                              hipStream_t stream) {
  const float* x   = (const float*)d_in[0];
  const int*   ei  = (const int*)d_in[1];
  const float* W0  = (const float*)d_in[2];
  const float* b0  = (const float*)d_in[3];
  const float* W1  = (const float*)d_in[4];
  const float* b1  = (const float*)d_in[5];
  const float* W2  = (const float*)d_in[6];
  const float* b2  = (const float*)d_in[7];
  const float* Wfc = (const float*)d_in[8];
  const float* bfc = (const float*)d_in[9];
  float* out = (float*)d_out;

  const int N = in_sizes[0] / FIN;       // 100000
  const int E = in_sizes[1] / 2;         // 1600000
  const int* src = ei;
  const int* dst = ei + E;
  const int KP0 = 512;                   // FIN padded to mult of 32

  // workspace layout
  char* ws = (char*)d_ws;
  size_t off = 0;
  int* cnt = (int*)(ws + off);            off = align_up(off + (size_t)N * 4, 512);
  float* dis = (float*)(ws + off);        off = align_up(off + (size_t)N * 4, 512);
  int* rp = (int*)(ws + off);             off = align_up(off + (size_t)(N + 1) * 4, 512);
  int* bsums = (int*)(ws + off);          off = align_up(off + 4096, 512);
  int* esrc = (int*)(ws + off);           off = align_up(off + (size_t)E * 4, 512);
  float* enorm = (float*)(ws + off);      off = align_up(off + (size_t)E * 4, 512);
  int2* epackL = (int2*)(ws + off);       off = align_up(off + (size_t)E * 8, 512);
  short* WT0 = (short*)(ws + off);        off = align_up(off + (size_t)128 * KP0 * 2, 512);
  short* WT1 = (short*)(ws + off);        off = align_up(off + (size_t)128 * FH * 2, 512);
  short* WT2 = (short*)(ws + off);        off = align_up(off + (size_t)128 * FH * 2, 512);
  short* WfcT = (short*)(ws + off);       off = align_up(off + (size_t)48 * FH * 2, 512);
  short* hA = (short*)(ws + off);         off = align_up(off + (size_t)N * FH * 2, 512);
  short* hB = (short*)(ws + off);         off = align_up(off + (size_t)N * FH * 2, 512);
  unsigned short* hQ = (unsigned short*)(ws + off); off = align_up(off + (size_t)N * 64 * 2, 512);
  float* scale = (float*)(ws + off);      off = align_up(off + (size_t)N * 4, 512);

  const int gE = (E + 255) / 256;
  const int gN = (N + 255) / 256;
  const int nbScan = (N + 1023) / 1024;
  const int gN4 = (N + 3) / 4;

  // --- CSR build ---
  hipMemsetAsync(cnt, 0, (size_t)N * 4, stream);
  k_hist<<<gE, 256, 0, stream>>>(dst, cnt, E);
  k_dis<<<gN, 256, 0, stream>>>(cnt, dis, N);
  k_scan1<<<nbScan, 256, 0, stream>>>(cnt, rp, bsums, N);
  k_scan2<<<1, 256, 0, stream>>>(bsums, nbScan);
  k_scan3<<<(N + 1 + 255) / 256, 256, 0, stream>>>(rp, bsums, N, E);
  hipMemsetAsync(cnt, 0, (size_t)N * 4, stream);
  k_scatter<<<gE, 256, 0, stream>>>(src, dst, dis, rp, cnt, esrc, enorm, E);

  // --- weight prep ---
  k_prep_w<<<(128 * KP0 + 255) / 256, 256, 0, stream>>>(W0, WT0, FIN, KP0);
  k_prep_w<<<(128 * FH + 255) / 256, 256, 0, stream>>>(W1, WT1, FH, FH);
  k_prep_w<<<(128 * FH + 255) / 256, 256, 0, stream>>>(W2, WT2, FH, FH);
  k_prep_wfc<<<(48 * FH + 255) / 256, 256, 0, stream>>>(Wfc, WfcT);

  const int gGemm = (N + 63) / 64;

  // --- layer 0: 500 -> 128 ---
  k_gemm_mfma<true><<<gGemm, 256, 0, stream>>>(x, WT0, hA, N, FIN, KP0);
  k_quant<<<gN4, 256, 0, stream>>>((const unsigned*)hA, hQ, scale, N);
  k_rescale<<<gE, 256, 0, stream>>>(esrc, enorm, scale, epackL, E);
  k_agg<<<gN4, 256, 0, stream>>>((const char*)hQ, (const char*)hA, (char*)hB, dis, rp, epackL, b0, N);
  // --- layer 1 ---
  k_gemm_mfma<false><<<gGemm, 256, 0, stream>>>(hB, WT1, hA, N, FH, FH);
  k_quant<<<gN4, 256, 0, stream>>>((const unsigned*)hA, hQ, scale, N);
  k_rescale<<<gE, 256, 0, stream>>>(esrc, enorm, scale, epackL, E);
  k_agg<<<gN4, 256, 0, stream>>>((const char*)hQ, (const char*)hA, (char*)hB, dis, rp, epackL, b1, N);
  // --- layer 2 ---
  k_gemm_mfma<false><<<gGemm, 256, 0, stream>>>(hB, WT2, hA, N, FH, FH);
  k_quant<<<gN4, 256, 0, stream>>>((const unsigned*)hA, hQ, scale, N);
  k_rescale<<<gE, 256, 0, stream>>>(esrc, enorm, scale, epackL, E);
  k_agg<<<gN4, 256, 0, stream>>>((const char*)hQ, (const char*)hA, (char*)hB, dis, rp, epackL, b2, N);
  // --- FC + log_softmax ---
  k_logits<<<gGemm, 256, 0, stream>>>(hB, WfcT, bfc, out, N);
}

// Round 6
// 434.931 us; speedup vs baseline: 1.2224x; 1.2224x over previous
//
#include <hip/hip_runtime.h>
#include <hip/hip_bf16.h>
#include <cstdint>
#include <cstddef>

#define FIN 500
#define FH  128
#define FOUT 40
#define NB 256      // buckets (dst >> 9), 512 nodes each

typedef __attribute__((ext_vector_type(8))) short short8;
typedef __attribute__((ext_vector_type(4))) float f32x4;

__device__ inline float bf_lo(unsigned v) { unsigned t = v << 16; return __builtin_bit_cast(float, t); }
__device__ inline float bf_hi(unsigned v) { unsigned t = v & 0xffff0000u; return __builtin_bit_cast(float, t); }
__device__ inline unsigned short f2bf_bits(float f) {
  __hip_bfloat16 b = __float2bfloat16(f);
  return __builtin_bit_cast(unsigned short, b);
}

// ================= bucketed CSR build =================
// Random scatter/atomic traffic is the killer (r5: k_scatter 125us, 155MB
// writebacks for 12.8MB payload). Bucket by dst>>9 so all random writes land
// in L2-resident windows.

// A: per-block LDS bucket histogram -> global bucketCnt
__global__ void __launch_bounds__(256) k_bcount(const int* __restrict__ dst,
                                                int* __restrict__ bucketCnt, int E) {
  __shared__ int lc[NB];
  int t = threadIdx.x;
  lc[t] = 0;
  __syncthreads();
  int base = blockIdx.x * 2048 + t * 8;
#pragma unroll
  for (int j = 0; j < 8; ++j) {
    int e = base + j;
    if (e < E) atomicAdd(&lc[dst[e] >> 9], 1);
  }
  __syncthreads();
  if (lc[t]) atomicAdd(&bucketCnt[t], lc[t]);
}

// exclusive scan of bucketCnt (256) -> bucketBase[257], base[256]=E
__global__ void k_bscan(const int* __restrict__ bucketCnt, int* __restrict__ bucketBase) {
  __shared__ int s[NB];
  int t = threadIdx.x;
  int v = bucketCnt[t];
  s[t] = v;
  __syncthreads();
  for (int o = 1; o < NB; o <<= 1) {
    int u = 0;
    if (t >= o) u = s[t - o];
    __syncthreads();
    if (t >= o) s[t] += u;
    __syncthreads();
  }
  bucketBase[t] = s[t] - v;
  if (t == NB - 1) bucketBase[NB] = s[NB - 1];
}

// B: bin edges bucket-major into ebin=(src,dst). LDS ranks + one global bump
// per (block,bucket) -> append-stream writes, L2-local.
__global__ void __launch_bounds__(256) k_bin(const int* __restrict__ src,
                                             const int* __restrict__ dst,
                                             const int* __restrict__ bucketBase,
                                             int* __restrict__ bucketFill,
                                             int2* __restrict__ ebin, int E) {
  __shared__ int lc[NB];
  __shared__ int lbb[NB];
  int t = threadIdx.x;
  lc[t] = 0;
  lbb[t] = bucketBase[t];
  __syncthreads();
  int base = blockIdx.x * 2048 + t * 8;
  int rk[8], bk[8], dd[8], ss[8];
#pragma unroll
  for (int j = 0; j < 8; ++j) {
    int e = base + j;
    if (e < E) {
      dd[j] = dst[e]; ss[j] = src[e];
      bk[j] = dd[j] >> 9;
      rk[j] = atomicAdd(&lc[bk[j]], 1);
    }
  }
  __syncthreads();
  int c = lc[t];
  int gb = 0;
  if (c) gb = atomicAdd(&bucketFill[t], c);
  __syncthreads();
  lc[t] = gb;
  __syncthreads();
#pragma unroll
  for (int j = 0; j < 8; ++j) {
    int e = base + j;
    if (e < E) {
      int pos = lbb[bk[j]] + lc[bk[j]] + rk[j];
      ebin[pos] = make_int2(ss[j], dd[j]);
    }
  }
}

// D: per-bucket exact-dst histogram in LDS -> cnt (replaces random-atomic k_hist)
__global__ void __launch_bounds__(512) k_bhist(const int2* __restrict__ ebin,
                                               const int* __restrict__ bucketBase,
                                               int* __restrict__ cnt, int N) {
  __shared__ int hc[512];
  int t = threadIdx.x, b = blockIdx.x;
  hc[t] = 0;
  __syncthreads();
  int s = bucketBase[b], e = bucketBase[b + 1];
  for (int i = s + t; i < e; i += 512) atomicAdd(&hc[ebin[i].y & 511], 1);
  __syncthreads();
  int idx = b * 512 + t;
  if (idx < N) cnt[idx] = hc[t];
}

// E: per-bucket final CSR scatter; rp/dis/fill windows in LDS; epackS writes
// land in an ~65KB L2-resident window.
__global__ void __launch_bounds__(512) k_fscatter(const int2* __restrict__ ebin,
                                                  const int* __restrict__ bucketBase,
                                                  const int* __restrict__ rp,
                                                  const float* __restrict__ dis,
                                                  int2* __restrict__ epackS, int N) {
  __shared__ int lrp[512];
  __shared__ float ldis[512];
  __shared__ int fill[512];
  int t = threadIdx.x, b = blockIdx.x;
  int n0 = b * 512 + t;
  lrp[t] = (n0 < N) ? rp[n0] : 0;
  ldis[t] = (n0 < N) ? dis[n0] : 0.f;
  fill[t] = 0;
  __syncthreads();
  int s = bucketBase[b], e = bucketBase[b + 1];
  for (int i = s + t; i < e; i += 512) {
    int2 ed = ebin[i];
    int ld = ed.y & 511;
    int r = atomicAdd(&fill[ld], 1);
    float nm = dis[ed.x] * ldis[ld];
    epackS[lrp[ld] + r] = make_int2(ed.x << 7, __builtin_bit_cast(int, nm));
  }
}

// ---------------- degree / scans (unchanged) ----------------

__global__ void k_dis(const int* __restrict__ cnt, float* __restrict__ dis, int n) {
  int i = blockIdx.x * 256 + threadIdx.x;
  if (i < n) dis[i] = rsqrtf((float)cnt[i] + 1.0f);  // deg includes self-loop
}

__global__ void k_scan1(const int* __restrict__ cnt, int* __restrict__ rp,
                        int* __restrict__ bsums, int n) {
  __shared__ int sums[256];
  int t = threadIdx.x;
  int base = blockIdx.x * 1024;
  int c[4]; int tot = 0;
#pragma unroll
  for (int j = 0; j < 4; ++j) {
    int idx = base + t * 4 + j;
    c[j] = (idx < n) ? cnt[idx] : 0;
    tot += c[j];
  }
  sums[t] = tot;
  __syncthreads();
  for (int off = 1; off < 256; off <<= 1) {
    int v = 0;
    if (t >= off) v = sums[t - off];
    __syncthreads();
    if (t >= off) sums[t] += v;
    __syncthreads();
  }
  int run = sums[t] - tot;
#pragma unroll
  for (int j = 0; j < 4; ++j) {
    int idx = base + t * 4 + j;
    if (idx < n) rp[idx] = run;
    run += c[j];
  }
  if (t == 255) bsums[blockIdx.x] = sums[255];
}

__global__ void k_scan2(int* __restrict__ bsums, int nb) {
  __shared__ int s[256];
  int t = threadIdx.x;
  int v = (t < nb) ? bsums[t] : 0;
  s[t] = v;
  __syncthreads();
  for (int off = 1; off < 256; off <<= 1) {
    int u = 0;
    if (t >= off) u = s[t - off];
    __syncthreads();
    if (t >= off) s[t] += u;
    __syncthreads();
  }
  if (t < nb) bsums[t] = s[t] - v;  // exclusive
}

__global__ void k_scan3(int* __restrict__ rp, const int* __restrict__ bsums, int n, int E) {
  int idx = blockIdx.x * 256 + threadIdx.x;
  if (idx < n) rp[idx] += bsums[idx >> 10];
  if (idx == n) rp[n] = E;
}

// per-layer: fold row scale into edge weight -> epackL = (byte_off, norm*scale[src])
__global__ void k_rescale(const int2* __restrict__ epackS, const float* __restrict__ scale,
                          int2* __restrict__ epackL, int E) {
  int e = blockIdx.x * 256 + threadIdx.x;
  if (e >= E) return;
  int2 p = epackS[e];
  float n = __builtin_bit_cast(float, p.y) * scale[p.x >> 7];
  epackL[e] = make_int2(p.x, __builtin_bit_cast(int, n));
}

// ---------------- weight prep ----------------

__global__ void k_prep_w(const float* __restrict__ W, short* __restrict__ WT, int K, int KPAD) {
  int idx = blockIdx.x * 256 + threadIdx.x;
  if (idx >= 128 * KPAD) return;
  int c = idx / KPAD, k = idx - c * KPAD;
  WT[idx] = (k < K) ? (short)f2bf_bits(W[(size_t)k * FH + c]) : (short)0;
}

__global__ void k_prep_wfc(const float* __restrict__ Wfc, short* __restrict__ WfcT) {
  int idx = blockIdx.x * 256 + threadIdx.x;
  if (idx >= 48 * 128) return;
  int c = idx >> 7, k = idx & 127;
  WfcT[idx] = (c < FOUT) ? (short)f2bf_bits(Wfc[(size_t)k * FOUT + c]) : (short)0;
}

// ---------------- per-row int8 quantize ----------------

__global__ void __launch_bounds__(256) k_quant(const unsigned* __restrict__ hA,
                                               unsigned short* __restrict__ hQ,
                                               float* __restrict__ scale, int N) {
  int node = blockIdx.x * 4 + (threadIdx.x >> 6);
  int lane = threadIdx.x & 63;
  if (node >= N) return;
  unsigned v = hA[(size_t)node * 64 + lane];
  float lo = bf_lo(v), hi = bf_hi(v);
  float m = fmaxf(fabsf(lo), fabsf(hi));
#pragma unroll
  for (int s = 1; s < 64; s <<= 1) m = fmaxf(m, __shfl_xor(m, s));
  float rs = (m > 0.f) ? 127.f / m : 0.f;
  int q0 = (int)rintf(lo * rs), q1 = (int)rintf(hi * rs);
  hQ[(size_t)node * 64 + lane] = (unsigned short)((q0 & 0xff) | ((q1 & 0xff) << 8));
  if (lane == 0) scale[node] = m * (1.f / 127.f);
}

// ---------------- MFMA GEMM (unchanged from r5) ----------------

template<bool AF32>
__global__ void __launch_bounds__(256) k_gemm_mfma(const void* __restrict__ Aptr,
                                                   const short* __restrict__ WT,
                                                   short* __restrict__ C,
                                                   int M, int K, int KPAD) {
  __shared__ char sA[2][64 * 80];
  __shared__ char sB[2][128 * 80];
  const int tid = threadIdx.x;
  const int r0 = blockIdx.x * 64;
  const int wave = tid >> 6, lane = tid & 63;
  const int wm = wave >> 1, wn = wave & 1;
  const int lr = lane & 15, g = lane >> 4;
  const int arow = tid >> 2, aq = tid & 3;
  const int bcol = tid >> 1, bh = tid & 1;

  f32x4 acc[2][4];
#pragma unroll
  for (int i = 0; i < 2; ++i)
#pragma unroll
    for (int j = 0; j < 4; ++j) acc[i][j] = (f32x4){0.f, 0.f, 0.f, 0.f};

  const int nkt = (K + 31) / 32;
  const int agr = (r0 + arow < M) ? (r0 + arow) : (M - 1);

  float4 fa0, fa1;
  short8 abf;
  short8 b0, b1;

  auto loadA = [&](int kt) {
    const int k0 = kt * 32 + aq * 8;
    if (AF32) {
      const float* A = (const float*)Aptr;
      if (k0 + 8 <= K) {
        const float4* ap = (const float4*)(A + (size_t)agr * K + k0);
        fa0 = ap[0]; fa1 = ap[1];
      } else {
        const float* ap = A + (size_t)agr * K;
        float t[8];
#pragma unroll
        for (int j = 0; j < 8; ++j) t[j] = (k0 + j < K) ? ap[k0 + j] : 0.f;
        fa0 = make_float4(t[0], t[1], t[2], t[3]);
        fa1 = make_float4(t[4], t[5], t[6], t[7]);
      }
    } else {
      const short* A = (const short*)Aptr;
      abf = *(const short8*)(A + (size_t)agr * K + k0);
    }
  };
  auto loadB = [&](int kt) {
    const int k0 = kt * 32 + bh * 16;
    const short8* wp = (const short8*)(WT + (size_t)bcol * KPAD + k0);
    b0 = wp[0]; b1 = wp[1];
  };
  auto stageLDS = [&](int buf) {
    short8 av;
    if (AF32) {
      float f[8] = {fa0.x, fa0.y, fa0.z, fa0.w, fa1.x, fa1.y, fa1.z, fa1.w};
#pragma unroll
      for (int j = 0; j < 8; ++j) av[j] = (short)f2bf_bits(f[j]);
    } else {
      av = abf;
    }
    *(short8*)(sA[buf] + arow * 80 + aq * 16) = av;
    *(short8*)(sB[buf] + bcol * 80 + bh * 32) = b0;
    *(short8*)(sB[buf] + bcol * 80 + bh * 32 + 16) = b1;
  };

  loadA(0); loadB(0);
  stageLDS(0);
  __syncthreads();
  for (int kt = 0; kt < nkt; ++kt) {
    const int cur = kt & 1;
    if (kt + 1 < nkt) { loadA(kt + 1); loadB(kt + 1); }
    short8 af[2], bfr[4];
#pragma unroll
    for (int i = 0; i < 2; ++i)
      af[i] = *(const short8*)(sA[cur] + (wm * 32 + i * 16 + lr) * 80 + g * 16);
#pragma unroll
    for (int j = 0; j < 4; ++j)
      bfr[j] = *(const short8*)(sB[cur] + (wn * 64 + j * 16 + lr) * 80 + g * 16);
#pragma unroll
    for (int i = 0; i < 2; ++i)
#pragma unroll
      for (int j = 0; j < 4; ++j)
        acc[i][j] = __builtin_amdgcn_mfma_f32_16x16x32_bf16(af[i], bfr[j], acc[i][j], 0, 0, 0);
    if (kt + 1 < nkt) stageLDS(cur ^ 1);
    __syncthreads();
  }
#pragma unroll
  for (int i = 0; i < 2; ++i) {
#pragma unroll
    for (int reg = 0; reg < 4; ++reg) {
      int gr = r0 + wm * 32 + i * 16 + g * 4 + reg;
      if (gr < M) {
#pragma unroll
        for (int j = 0; j < 4; ++j) {
          int gc = wn * 64 + j * 16 + lr;
          C[(size_t)gr * FH + gc] = (short)f2bf_bits(acc[i][j][reg]);
        }
      }
    }
  }
}

// ---------------- aggregation v5: int8 gather + epack prefetch pipeline ----------------
// As v4 (2 edges/instr via lane halves, bpermute distribution) but the next
// iteration's edge packs are loaded BEFORE consuming the current ones, taking
// the epack load off the serial epack->bpermute->gather chain.

__global__ void __launch_bounds__(256) k_agg(const char* __restrict__ hQbytes,
                                             const char* __restrict__ hAbytes,
                                             char* __restrict__ outbytes,
                                             const float* __restrict__ dis,
                                             const int* __restrict__ rp,
                                             const int2* __restrict__ epackL,
                                             const float* __restrict__ bias,
                                             int N) {
  int node = blockIdx.x * 4 + (threadIdx.x >> 6);
  int lane = threadIdx.x & 63;
  if (node >= N) return;
  const int q = lane & 31;
  const int hi = lane >> 5;
  const int e0 = rp[node], end = rp[node + 1];
  int2 p = make_int2(0, 0);
  if (lane < 16 && e0 + lane < end) p = epackL[e0 + lane];
  float a0 = 0.f, a1 = 0.f, a2 = 0.f, a3 = 0.f;
  if (hi == 0) {
    float w = dis[node]; w = w * w;
    uint2 sv = *(const uint2*)(hAbytes + (size_t)node * 256 + q * 8);
    a0 = w * bf_lo(sv.x); a1 = w * bf_hi(sv.x);
    a2 = w * bf_lo(sv.y); a3 = w * bf_hi(sv.y);
  }
  const int vbp = hi * 4;
  for (int e = e0; e < end; e += 16) {
    int2 pn = make_int2(0, 0);
    if (lane < 16 && e + 16 + lane < end) pn = epackL[e + 16 + lane];  // prefetch
    int vv[8]; float nn[8];
#pragma unroll
    for (int j = 0; j < 8; ++j) {
      int idx4 = vbp + 8 * j;
      int off = __builtin_amdgcn_ds_bpermute(idx4, p.x);
      int nb  = __builtin_amdgcn_ds_bpermute(idx4, p.y);
      nn[j] = __builtin_bit_cast(float, nb);
      vv[j] = *(const int*)(hQbytes + (size_t)(unsigned)(off + q * 4));
    }
#pragma unroll
    for (int j = 0; j < 8; ++j) {
      int d = vv[j];
      float n = nn[j];
      a0 += n * (float)((d << 24) >> 24);
      a1 += n * (float)((d << 16) >> 24);
      a2 += n * (float)((d << 8) >> 24);
      a3 += n * (float)(d >> 24);
    }
    p = pn;
  }
  a0 += __shfl_xor(a0, 32); a1 += __shfl_xor(a1, 32);
  a2 += __shfl_xor(a2, 32); a3 += __shfl_xor(a3, 32);
  if (hi == 0) {
    float4 bv = *(const float4*)(bias + 4 * q);
    a0 = fmaxf(a0 + bv.x, 0.f); a1 = fmaxf(a1 + bv.y, 0.f);
    a2 = fmaxf(a2 + bv.z, 0.f); a3 = fmaxf(a3 + bv.w, 0.f);
    uint2 r;
    r.x = ((unsigned)f2bf_bits(a1) << 16) | (unsigned)f2bf_bits(a0);
    r.y = ((unsigned)f2bf_bits(a3) << 16) | (unsigned)f2bf_bits(a2);
    *(uint2*)(outbytes + (size_t)node * 256 + q * 8) = r;
  }
}

// ---------------- fused logits + log_softmax via MFMA ----------------

__global__ void __launch_bounds__(256) k_logits(const short* __restrict__ h,
                                                const short* __restrict__ WfcT,
                                                const float* __restrict__ bfc,
                                                float* __restrict__ out, int N) {
  const int wave = threadIdx.x >> 6, lane = threadIdx.x & 63;
  const int lr = lane & 15, g = lane >> 4;
  const int nbase = blockIdx.x * 64 + wave * 16;
  int arow = nbase + lr; if (arow >= N) arow = N - 1;
  const short* ap = h + (size_t)arow * FH;
  short8 af[4];
#pragma unroll
  for (int ks = 0; ks < 4; ++ks)
    af[ks] = *(const short8*)(ap + ks * 32 + g * 8);
  f32x4 acc[3];
#pragma unroll
  for (int t = 0; t < 3; ++t) {
    acc[t] = (f32x4){0.f, 0.f, 0.f, 0.f};
    const short* bp = WfcT + (size_t)(t * 16 + lr) * FH;
#pragma unroll
    for (int ks = 0; ks < 4; ++ks) {
      short8 bf = *(const short8*)(bp + ks * 32 + g * 8);
      acc[t] = __builtin_amdgcn_mfma_f32_16x16x32_bf16(af[ks], bf, acc[t], 0, 0, 0);
    }
  }
  float bb[3];
#pragma unroll
  for (int t = 0; t < 3; ++t) { int c = t * 16 + lr; bb[t] = (c < FOUT) ? bfc[c] : 0.f; }
  const bool v2 = (lr < 8);
  float res[3][4];
#pragma unroll
  for (int r = 0; r < 4; ++r) {
    float l0 = acc[0][r] + bb[0];
    float l1 = acc[1][r] + bb[1];
    float l2 = v2 ? (acc[2][r] + bb[2]) : -INFINITY;
    float mm = fmaxf(fmaxf(l0, l1), l2);
#pragma unroll
    for (int s = 1; s < 16; s <<= 1) mm = fmaxf(mm, __shfl_xor(mm, s));
    float e0 = expf(l0 - mm), e1 = expf(l1 - mm), e2 = v2 ? expf(l2 - mm) : 0.f;
    float ss = e0 + e1 + e2;
#pragma unroll
    for (int s = 1; s < 16; s <<= 1) ss += __shfl_xor(ss, s);
    float lse = mm + logf(ss);
    res[0][r] = l0 - lse; res[1][r] = l1 - lse; res[2][r] = l2 - lse;
  }
#pragma unroll
  for (int t = 0; t < 3; ++t) {
    int c = t * 16 + lr;
    if (c < FOUT) {
#pragma unroll
      for (int r = 0; r < 4; ++r) {
        int node = nbase + g * 4 + r;
        if (node < N) out[(size_t)node * FOUT + c] = res[t][r];
      }
    }
  }
}

// ---------------- host ----------------

static inline size_t align_up(size_t x, size_t a) { return (x + a - 1) & ~(a - 1); }

extern "C" void kernel_launch(void* const* d_in, const int* in_sizes, int n_in,
                              void* d_out, int out_size, void* d_ws, size_t ws_size,
                              hipStream_t stream) {
  const float* x   = (const float*)d_in[0];
  const int*   ei  = (const int*)d_in[1];
  const float* W0  = (const float*)d_in[2];
  const float* b0  = (const float*)d_in[3];
  const float* W1  = (const float*)d_in[4];
  const float* b1  = (const float*)d_in[5];
  const float* W2  = (const float*)d_in[6];
  const float* b2  = (const float*)d_in[7];
  const float* Wfc = (const float*)d_in[8];
  const float* bfc = (const float*)d_in[9];
  float* out = (float*)d_out;

  const int N = in_sizes[0] / FIN;       // 100000
  const int E = in_sizes[1] / 2;         // 1600000
  const int* src = ei;
  const int* dst = ei + E;
  const int KP0 = 512;

  // workspace layout
  char* ws = (char*)d_ws;
  size_t off = 0;
  int* cnt = (int*)(ws + off);            off = align_up(off + (size_t)N * 4, 512);
  float* dis = (float*)(ws + off);        off = align_up(off + (size_t)N * 4, 512);
  int* rp = (int*)(ws + off);             off = align_up(off + (size_t)(N + 1) * 4, 512);
  int* bsums = (int*)(ws + off);          off = align_up(off + 4096, 512);
  int* bucketCnt = (int*)(ws + off);      off = align_up(off + (NB + 1) * 4, 512);
  int* bucketBase = (int*)(ws + off);     off = align_up(off + (NB + 1) * 4, 512);
  int* bucketFill = (int*)(ws + off);     off = align_up(off + (NB + 1) * 4, 512);
  int2* ebin = (int2*)(ws + off);         off = align_up(off + (size_t)E * 8, 512);
  int2* epackS = (int2*)(ws + off);       off = align_up(off + (size_t)E * 8, 512);
  int2* epackL = (int2*)(ws + off);       off = align_up(off + (size_t)E * 8, 512);
  short* WT0 = (short*)(ws + off);        off = align_up(off + (size_t)128 * KP0 * 2, 512);
  short* WT1 = (short*)(ws + off);        off = align_up(off + (size_t)128 * FH * 2, 512);
  short* WT2 = (short*)(ws + off);        off = align_up(off + (size_t)128 * FH * 2, 512);
  short* WfcT = (short*)(ws + off);       off = align_up(off + (size_t)48 * FH * 2, 512);
  short* hA = (short*)(ws + off);         off = align_up(off + (size_t)N * FH * 2, 512);
  short* hB = (short*)(ws + off);         off = align_up(off + (size_t)N * FH * 2, 512);
  float* scale = (float*)(ws + off);      off = align_up(off + (size_t)N * 4, 512);
  // hQ aliases ebin (ebin is dead once k_fscatter completes; hQ first written after)
  unsigned short* hQ = (unsigned short*)ebin;

  const int gE = (E + 255) / 256;
  const int nbScan = (N + 1023) / 1024;
  const int gN4 = (N + 3) / 4;
  const int gBlk = (E + 2047) / 2048;        // k_bcount / k_bin
  const int NBUSE = (N + 511) / 512;         // 196 buckets in use

  // --- bucketed CSR build ---
  hipMemsetAsync(bucketCnt, 0, (NB + 1) * 4, stream);
  hipMemsetAsync(bucketFill, 0, (NB + 1) * 4, stream);
  k_bcount<<<gBlk, 256, 0, stream>>>(dst, bucketCnt, E);
  k_bscan<<<1, NB, 0, stream>>>(bucketCnt, bucketBase);
  k_bin<<<gBlk, 256, 0, stream>>>(src, dst, bucketBase, bucketFill, ebin, E);
  k_bhist<<<NBUSE, 512, 0, stream>>>(ebin, bucketBase, cnt, N);
  k_dis<<<(N + 255) / 256, 256, 0, stream>>>(cnt, dis, N);
  k_scan1<<<nbScan, 256, 0, stream>>>(cnt, rp, bsums, N);
  k_scan2<<<1, 256, 0, stream>>>(bsums, nbScan);
  k_scan3<<<(N + 1 + 255) / 256, 256, 0, stream>>>(rp, bsums, N, E);
  k_fscatter<<<NBUSE, 512, 0, stream>>>(ebin, bucketBase, rp, dis, epackS, N);

  // --- weight prep ---
  k_prep_w<<<(128 * KP0 + 255) / 256, 256, 0, stream>>>(W0, WT0, FIN, KP0);
  k_prep_w<<<(128 * FH + 255) / 256, 256, 0, stream>>>(W1, WT1, FH, FH);
  k_prep_w<<<(128 * FH + 255) / 256, 256, 0, stream>>>(W2, WT2, FH, FH);
  k_prep_wfc<<<(48 * FH + 255) / 256, 256, 0, stream>>>(Wfc, WfcT);

  const int gGemm = (N + 63) / 64;

  // --- layer 0: 500 -> 128 ---
  k_gemm_mfma<true><<<gGemm, 256, 0, stream>>>(x, WT0, hA, N, FIN, KP0);
  k_quant<<<gN4, 256, 0, stream>>>((const unsigned*)hA, hQ, scale, N);
  k_rescale<<<gE, 256, 0, stream>>>(epackS, scale, epackL, E);
  k_agg<<<gN4, 256, 0, stream>>>((const char*)hQ, (const char*)hA, (char*)hB, dis, rp, epackL, b0, N);
  // --- layer 1 ---
  k_gemm_mfma<false><<<gGemm, 256, 0, stream>>>(hB, WT1, hA, N, FH, FH);
  k_quant<<<gN4, 256, 0, stream>>>((const unsigned*)hA, hQ, scale, N);
  k_rescale<<<gE, 256, 0, stream>>>(epackS, scale, epackL, E);
  k_agg<<<gN4, 256, 0, stream>>>((const char*)hQ, (const char*)hA, (char*)hB, dis, rp, epackL, b1, N);
  // --- layer 2 ---
  k_gemm_mfma<false><<<gGemm, 256, 0, stream>>>(hB, WT2, hA, N, FH, FH);
  k_quant<<<gN4, 256, 0, stream>>>((const unsigned*)hA, hQ, scale, N);
  k_rescale<<<gE, 256, 0, stream>>>(epackS, scale, epackL, E);
  k_agg<<<gN4, 256, 0, stream>>>((const char*)hQ, (const char*)hA, (char*)hB, dis, rp, epackL, b2, N);
  // --- FC + log_softmax ---
  k_logits<<<gGemm, 256, 0, stream>>>(hB, WfcT, bfc, out, N);
}